// Round 16
// baseline (824.390 us; speedup 1.0000x reference)
//
#include <hip/hip_runtime.h>
#include <math.h>

typedef unsigned short u16;
typedef __attribute__((ext_vector_type(4))) u16 u16x4;
typedef __attribute__((ext_vector_type(8))) u16 u16x8;
typedef __attribute__((ext_vector_type(8))) __bf16 bf16x8;
typedef __attribute__((ext_vector_type(4))) float f32x4;
typedef __attribute__((ext_vector_type(16))) float f32x16;
typedef __attribute__((ext_vector_type(4))) unsigned u32x4;

#define D_MODEL 2048
#define SEQ 2048
#define BATCH 2
#define NH 16
#define HD 128
#define DFF 8192
#define ROWS (BATCH * SEQ)  // 4096

__device__ __forceinline__ u16 f2bf(float f) {
  union { float f; unsigned u; } v; v.f = f;
  unsigned r = v.u + 0x7FFFu + ((v.u >> 16) & 1u);
  return (u16)(r >> 16);
}
__device__ __forceinline__ u16 to_bf16(float f) { return f2bf(f); }
__device__ __forceinline__ u16 to_bf16(u16 v) { return v; }

__device__ __forceinline__ f32x4 mfma16(u16x8 a, u16x8 b, f32x4 c) {
  return __builtin_amdgcn_mfma_f32_16x16x32_bf16(
      __builtin_bit_cast(bf16x8, a), __builtin_bit_cast(bf16x8, b), c, 0, 0, 0);
}
__device__ __forceinline__ f32x16 mfma32(u16x8 a, u16x8 b, f32x16 c) {
  return __builtin_amdgcn_mfma_f32_32x32x16_bf16(
      __builtin_bit_cast(bf16x8, a), __builtin_bit_cast(bf16x8, b), c, 0, 0, 0);
}

__device__ __forceinline__ void gll16(const void* g, void* l) {
  __builtin_amdgcn_global_load_lds(
      (const __attribute__((address_space(1))) void*)g,
      (__attribute__((address_space(3))) void*)l, 16, 0, 0);
}

// ---------------- fp32 -> bf16 bulk cast ----------------
__global__ __launch_bounds__(256) void cast_kernel(const float* __restrict__ in,
                                                   u16* __restrict__ out, int n8) {
  int i = blockIdx.x * 256 + threadIdx.x;
  if (i >= n8) return;
  const float4* p = (const float4*)in + (size_t)i * 2;
  float4 a = p[0], b = p[1];
  u16x8 o;
  o[0] = f2bf(a.x); o[1] = f2bf(a.y); o[2] = f2bf(a.z); o[3] = f2bf(a.w);
  o[4] = f2bf(b.x); o[5] = f2bf(b.y); o[6] = f2bf(b.z); o[7] = f2bf(b.w);
  *((u16x8*)out + i) = o;
}

// --------- fused fp32 [K][N] -> bf16 [N][K] transpose-cast, all 6 weights ---
struct WTArgs {
  const float* src[6];
  u16* dst[6];
  int K[6], N[6];
  int start[7];
};

__global__ __launch_bounds__(256) void cast_transpose_all(WTArgs a) {
  __shared__ float tile[64][69];
  int b = blockIdx.x;
  int wi = 0;
#pragma unroll
  for (int i = 0; i < 6; ++i)
    if (b >= a.start[i + 1]) wi = i + 1;
  const float* src = a.src[wi];
  u16* dst = a.dst[wi];
  int K = a.K[wi], N = a.N[wi];
  int t = b - a.start[wi];
  int cols = N >> 6;
  int n0 = (t % cols) * 64, k0 = (t / cols) * 64;
  int rr = threadIdx.x >> 4, cc = (threadIdx.x & 15) * 4;
#pragma unroll
  for (int pp = 0; pp < 4; ++pp) {
    int kk = pp * 16 + rr;
    *(float4*)&tile[kk][cc] = *(const float4*)(src + (size_t)(k0 + kk) * N + n0 + cc);
  }
  __syncthreads();
#pragma unroll
  for (int pp = 0; pp < 4; ++pp) {
    int d = pp * 16 + rr;
    u16x4 w;
#pragma unroll
    for (int j = 0; j < 4; ++j) w[j] = f2bf(tile[cc + j][d]);
    *(u16x4*)(dst + (size_t)(n0 + d) * K + k0 + cc) = w;
  }
}

// ---------------- build V^T (cross only): [SEQ][128] -> [128][SEQ] bf16 -----
template <typename ST>
__global__ __launch_bounds__(256) void build_vt_kernel(
    const ST* __restrict__ src, u16* __restrict__ dst, int HZ,
    size_t src_b_stride, size_t src_h_stride, int src_tok_stride) {
  __shared__ u16 tl[64][72];
  int z = blockIdx.z, zb = z / HZ, zh = z % HZ;
  const ST* s = src + (size_t)zb * src_b_stride + (size_t)zh * src_h_stride;
  int t0 = blockIdx.x * 64, d0 = blockIdx.y * 64;
  int rr = threadIdx.x >> 4, cc = (threadIdx.x & 15) * 4;
#pragma unroll
  for (int pp = 0; pp < 4; ++pp) {
    int t = pp * 16 + rr;
    const ST* sp = s + (size_t)(t0 + t) * src_tok_stride + d0 + cc;
#pragma unroll
    for (int j = 0; j < 4; ++j) tl[t][cc + j] = to_bf16(sp[j]);
  }
  __syncthreads();
  u16* dp = dst + (size_t)z * HD * SEQ;
#pragma unroll
  for (int pp = 0; pp < 4; ++pp) {
    int d = pp * 16 + rr;
    u16x4 w;
#pragma unroll
    for (int j = 0; j < 4; ++j) w[j] = tl[cc + j][d];
    *(u16x4*)(dp + (size_t)(d0 + d) * SEQ + t0 + cc) = w;
  }
}

// ---------------- RMSNorm (fp32 in, bf16 out) ----------------
__global__ __launch_bounds__(256) void rmsnorm_kernel(const float* __restrict__ x,
                                                      const float* __restrict__ w,
                                                      u16* __restrict__ out) {
  __shared__ float red[4];
  int row = blockIdx.x, t = threadIdx.x;
  const float4* xr = (const float4*)(x + (size_t)row * D_MODEL);
  float4 a = xr[t * 2], b = xr[t * 2 + 1];
  float ss = a.x * a.x + a.y * a.y + a.z * a.z + a.w * a.w +
             b.x * b.x + b.y * b.y + b.z * b.z + b.w * b.w;
#pragma unroll
  for (int m = 1; m < 64; m <<= 1) ss += __shfl_xor(ss, m, 64);
  if ((t & 63) == 0) red[t >> 6] = ss;
  __syncthreads();
  float tot = red[0] + red[1] + red[2] + red[3];
  float sc = rsqrtf(tot * (1.0f / D_MODEL) + 1e-6f);
  const float4* wr = (const float4*)w;
  float4 wa = wr[t * 2], wb = wr[t * 2 + 1];
  u16x8 o;
  o[0] = f2bf(a.x * sc * wa.x); o[1] = f2bf(a.y * sc * wa.y);
  o[2] = f2bf(a.z * sc * wa.z); o[3] = f2bf(a.w * sc * wa.w);
  o[4] = f2bf(b.x * sc * wb.x); o[5] = f2bf(b.y * sc * wb.y);
  o[6] = f2bf(b.z * sc * wb.z); o[7] = f2bf(b.w * sc * wb.w);
  *((u16x8*)(out + (size_t)row * D_MODEL) + t) = o;
}

// ---------------- split-K combine (only ffn_w2) ----------------
template <int MODE>
__global__ __launch_bounds__(256) void combine_kernel(
    const float* __restrict__ p0, const float* __restrict__ p1,
    const float* __restrict__ res, void* __restrict__ outv, int n4) {
  int i = blockIdx.x * 256 + threadIdx.x;
  if (i >= n4) return;
  float4 a = ((const float4*)p0)[i];
  float4 b = ((const float4*)p1)[i];
  if (MODE == 1) {
    float4 r = ((const float4*)res)[i];
    float4 o;
    o.x = r.x + a.x + b.x; o.y = r.y + a.y + b.y;
    o.z = r.z + a.z + b.z; o.w = r.w + a.w + b.w;
    ((float4*)outv)[i] = o;
  } else {
    u16x4 o;
    o[0] = f2bf(a.x + b.x); o[1] = f2bf(a.y + b.y);
    o[2] = f2bf(a.z + b.z); o[3] = f2bf(a.w + b.w);
    ((u16x4*)outv)[i] = o;
  }
}

// ============ 256x256 8-wave pipelined GEMM (round-14 verified BEST) ========
// 4 phases/K-tile, ds_read prefetch in odd phases, waits only at odd phases.
#define LOADFRAGS(BASE)                                                        \
  {                                                                            \
    const u16* SA = S + (BASE);                                                \
    const u16* SB = SA + 8192;                                                 \
    _Pragma("unroll") for (int m = 0; m < 8; ++m) {                            \
      int row = wm * 128 + m * 16 + r16;                                       \
      aF[m] = *(const u16x8*)(SA + row * 32 + ((kg ^ ((row >> 1) & 3)) << 3)); \
    }                                                                          \
    _Pragma("unroll") for (int n = 0; n < 4; ++n) {                            \
      int row = wn * 64 + n * 16 + r16;                                        \
      bF[n] = *(const u16x8*)(SB + row * 32 + ((kg ^ ((row >> 1) & 3)) << 3)); \
    }                                                                          \
  }

#define MFMA_HALF(HH)                                                          \
  __builtin_amdgcn_s_setprio(1);                                               \
  _Pragma("unroll") for (int m = 0; m < 8; ++m) {                              \
    acc[m][2 * (HH)] = mfma16(aF[m], bF[2 * (HH)], acc[m][2 * (HH)]);          \
    acc[m][2 * (HH) + 1] =                                                     \
        mfma16(aF[m], bF[2 * (HH) + 1], acc[m][2 * (HH) + 1]);                 \
  }                                                                            \
  __builtin_amdgcn_s_setprio(0);

#define GPH_E(T, P, VM, DOW, ISSUE, FIRST)                                     \
  {                                                                            \
    if (ISSUE) issue_half(4 * (T) + (P) + 4);                                  \
    if (DOW) {                                                                 \
      asm volatile("s_waitcnt vmcnt(" #VM ")" ::: "memory");                   \
      __builtin_amdgcn_sched_barrier(0);                                       \
    }                                                                          \
    __builtin_amdgcn_s_barrier();                                              \
    if (FIRST) LOADFRAGS((((((T) & 1) << 2) | (P)) << 13));                    \
    MFMA_HALF(0)                                                               \
    __builtin_amdgcn_s_barrier();                                              \
  }

#define GPH_O(T, P, VM, DOW, ISSUE, PF)                                        \
  {                                                                            \
    if (ISSUE) issue_half(4 * (T) + (P) + 4);                                  \
    if (DOW) {                                                                 \
      asm volatile("s_waitcnt vmcnt(" #VM ")" ::: "memory");                   \
      __builtin_amdgcn_sched_barrier(0);                                       \
    }                                                                          \
    __builtin_amdgcn_s_barrier();                                              \
    MFMA_HALF(1)                                                               \
    if (PF) {                                                                  \
      if ((P) == 1) {                                                          \
        LOADFRAGS((((((T) & 1) << 2) | 2) << 13));                             \
      } else {                                                                 \
        LOADFRAGS(((((T) + 1) & 1) << 2) << 13);                               \
      }                                                                        \
    }                                                                          \
    __builtin_amdgcn_s_barrier();                                              \
  }

template <int EPI, int SPLIT>
__global__ __launch_bounds__(512, 1) void gemm256_kernel(
    const u16* __restrict__ A, const u16* __restrict__ Bt, void* __restrict__ Cv,
    float* __restrict__ Cv2, const float* __restrict__ res, int N, int K) {
  __shared__ __align__(16) u16 S[8 * 8192];
  const int tid = threadIdx.x, lane = tid & 63, wave = tid >> 6;
  const int wm = wave >> 2, wn = wave & 3;
  const int r16 = lane & 15, kg = lane >> 4;
  const int cols = N >> 8;
  const int cpx = gridDim.x >> 3;
  const int bid = blockIdx.x;
  const int swz = (bid & 7) * cpx + (bid >> 3);
  const int tiles = gridDim.x / SPLIT;
  const int tile = swz % tiles, kslice = swz / tiles;
  const int bm = (tile / cols) * 256, bn = (tile % cols) * 256;
  const int Ksub = K / SPLIT;
  const int koff = kslice * Ksub;
  const int nt = Ksub >> 6;

  auto issue_half = [&](int h) {
    int p = h & 3, t = h >> 2;
    const u16* src = (p & 1) ? (Bt + (size_t)bn * K) : (A + (size_t)bm * K);
    int kbase = koff + t * 64 + (p >> 1) * 32;
    u16* ldst = S + ((((t & 1) << 2) | p) << 13);
#pragma unroll
    for (int i = 0; i < 2; ++i) {
      int c = i * 512 + tid;
      int row = c >> 2, ch = c & 3;
      int kc = ch ^ ((row >> 1) & 3);
      gll16(src + (size_t)row * K + kbase + kc * 8, ldst + c * 8);
    }
  };

  u16x8 aF[8], bF[4];
  f32x4 acc[8][4] = {};

  issue_half(0); issue_half(1); issue_half(2); issue_half(3);
  GPH_E(0, 0, 6, true, true, true);
  GPH_O(0, 1, 4, true, true, true);
  GPH_E(0, 2, 0, false, true, false);
  GPH_O(0, 3, 4, true, true, true);
  for (int t = 1; t < nt - 1; ++t) {
    GPH_E(t, 0, 0, false, true, false);
    GPH_O(t, 1, 4, true, true, true);
    GPH_E(t, 2, 0, false, true, false);
    GPH_O(t, 3, 4, true, true, true);
  }
  {
    const int t = nt - 1;
    GPH_E(t, 0, 0, false, false, false);
    GPH_O(t, 1, 0, true, false, true);
    GPH_E(t, 2, 0, false, false, false);
    GPH_O(t, 3, 0, false, false, false);
  }

  float* Pp = (EPI == 3) ? (kslice ? Cv2 : (float*)Cv) : nullptr;
#pragma unroll
  for (int m = 0; m < 8; ++m) {
    int r0 = bm + wm * 128 + m * 16 + kg * 4;
#pragma unroll
    for (int n = 0; n < 4; ++n) {
      int cc = bn + wn * 64 + n * 16 + r16;
#pragma unroll
      for (int r = 0; r < 4; ++r) {
        size_t idx = (size_t)(r0 + r) * N + cc;
        float v = acc[m][n][r];
        if (EPI == 3) {
          Pp[idx] = v;
        } else if (EPI == 1) {
          ((float*)Cv)[idx] = res[idx] + v;
        } else if (EPI == 0) {
          ((u16*)Cv)[idx] = f2bf(v);
        } else {
          float s = v / (1.0f + __expf(-v));
          ((u16*)Cv)[idx] = f2bf(s);
        }
      }
    }
  }
}

// ============ 256x128 GEMM, 2-region double-buffer, 2 blocks/CU =============
// Verified round-9 schedule; NEW (r16): SPLIT template for split-K (koff into
// issue stream only). EPI: 0 bf16, 1 f32+res, 3 f32 partial (kslice->Cv/vt),
// 4 qkv+V^T.
#define NPH2(T, P, VM, ISSUE)                                                  \
  {                                                                            \
    if (ISSUE) issue_pair(2 * (T) + (P) + 1);                                  \
    asm volatile("s_waitcnt vmcnt(" #VM ")" ::: "memory");                     \
    __builtin_amdgcn_sched_barrier(0);                                         \
    __builtin_amdgcn_s_barrier();                                              \
    const u16* SA = S + (((2 * (T) + (P)) & 1) * 12288);                       \
    const u16* SB = SA + 8192;                                                 \
    u16x8 aF[4], bF[4];                                                        \
    _Pragma("unroll") for (int m = 0; m < 4; ++m) {                            \
      int row = wm * 64 + m * 16 + r16;                                        \
      aF[m] = *(const u16x8*)(SA + row * 32 + ((kg ^ ((row >> 1) & 3)) << 3)); \
    }                                                                          \
    _Pragma("unroll") for (int n = 0; n < 4; ++n) {                            \
      int row = wn * 64 + n * 16 + r16;                                        \
      bF[n] = *(const u16x8*)(SB + row * 32 + ((kg ^ ((row >> 1) & 3)) << 3)); \
    }                                                                          \
    __builtin_amdgcn_s_setprio(1);                                             \
    _Pragma("unroll") for (int m = 0; m < 4; ++m)                              \
      _Pragma("unroll") for (int n = 0; n < 4; ++n)                            \
        acc[m][n] = mfma16(aF[m], bF[n], acc[m][n]);                           \
    __builtin_amdgcn_s_setprio(0);                                             \
    __builtin_amdgcn_s_barrier();                                              \
  }

template <int EPI, int SPLIT>
__global__ __launch_bounds__(512, 4) void gemm_n128_kernel(
    const u16* __restrict__ A, const u16* __restrict__ Bt, void* __restrict__ Cv,
    const float* __restrict__ res, u16* __restrict__ vt, int N, int K) {
  __shared__ __align__(16) u16 S[2 * 12288];  // 48 KB
  const int tid = threadIdx.x, lane = tid & 63, wave = tid >> 6;
  const int wm = wave >> 1, wn = wave & 1;
  const int r16 = lane & 15, kg = lane >> 4;
  const int cols = N >> 7;
  const int cpx = gridDim.x >> 3;
  const int bid = blockIdx.x;
  const int swz = (bid & 7) * cpx + (bid >> 3);
  const int tiles = gridDim.x / SPLIT;
  const int tile = swz % tiles, kslice = swz / tiles;
  const int bm = (tile / cols) * 256, bn = (tile % cols) * 128;
  const int Ksub = K / SPLIT;
  const int koff = kslice * Ksub;
  const int nt = Ksub >> 6;

  auto issue_pair = [&](int g) {
    int p = g & 1, t = g >> 1;
    int kbase = koff + t * 64 + p * 32;
    u16* reg = S + ((g & 1) * 12288);
#pragma unroll
    for (int i = 0; i < 2; ++i) {
      int c = i * 512 + tid;
      int row = c >> 2, ch = c & 3;
      int kc = ch ^ ((row >> 1) & 3);
      gll16(A + (size_t)(bm + row) * K + kbase + kc * 8, reg + c * 8);
    }
    {
      int row = tid >> 2, ch = tid & 3;
      int kc = ch ^ ((row >> 1) & 3);
      gll16(Bt + (size_t)(bn + row) * K + kbase + kc * 8, reg + 8192 + tid * 8);
    }
  };

  f32x4 acc[4][4] = {};

  issue_pair(0);
  for (int t = 0; t < nt - 1; ++t) {
    NPH2(t, 0, 3, true);
    NPH2(t, 1, 3, true);
  }
  NPH2(nt - 1, 0, 3, true);
  NPH2(nt - 1, 1, 0, false);

  const bool vmode = (EPI == 4) && (bn >= 4096);
  float* Pp = (EPI == 3) ? (kslice ? (float*)vt : (float*)Cv) : nullptr;
#pragma unroll
  for (int m = 0; m < 4; ++m) {
    int r0 = bm + wm * 64 + m * 16 + kg * 4;
#pragma unroll
    for (int n = 0; n < 4; ++n) {
      int cc = bn + wn * 64 + n * 16 + r16;
      if (vmode) {
        int c2 = cc - 4096;
        int z = (r0 >> 11) * NH + (c2 >> 7);
        int d = c2 & 127;
        int t0 = r0 & (SEQ - 1);
        u16x4 w;
#pragma unroll
        for (int r = 0; r < 4; ++r) w[r] = f2bf(acc[m][n][r]);
        *(u16x4*)(vt + ((size_t)z * HD + d) * SEQ + t0) = w;
      } else {
#pragma unroll
        for (int r = 0; r < 4; ++r) {
          size_t idx = (size_t)(r0 + r) * N + cc;
          float v = acc[m][n][r];
          if (EPI == 3) {
            Pp[idx] = v;
          } else if (EPI == 1) {
            ((float*)Cv)[idx] = res[idx] + v;
          } else {
            ((u16*)Cv)[idx] = f2bf(v);
          }
        }
      }
    }
  }
}

// ---------------- flash attention v3: K/V double-buffered (verified r11) ----
template <bool CAUSAL, bool SELF>
__global__ __launch_bounds__(512, 2) void attn2_kernel(
    const u16* __restrict__ qp, const u16* __restrict__ kp,
    const u16* __restrict__ vtp, u16* __restrict__ outp) {
  __shared__ __align__(16) u16 Kl[2 * 64 * 128];   // 32 KB
  __shared__ __align__(16) u16 Vl[2 * 128 * 64];   // 32 KB
  const int tid = threadIdx.x, lane = tid & 63, wave = tid >> 6;
  const int lo = lane & 31, hi = lane >> 5;
  const int qt = blockIdx.x, bh = blockIdx.y, b = bh >> 4, h = bh & 15;
  const int qw0 = qt * 256 + wave * 32;
  const int qg = qw0 + lo;
  const size_t qstr = SELF ? 6144 : 2048;
  const size_t kstr = SELF ? 6144 : 512;
  const u16* qbase = qp + ((size_t)b * SEQ + qg) * qstr + h * HD;
  const u16* kbase = kp + (size_t)b * SEQ * kstr + (SELF ? (2048 + h * HD) : ((h >> 2) * HD));
  const u16* vbase = vtp + (size_t)(SELF ? (b * NH + h) : (b * 4 + (h >> 2))) * HD * SEQ;

  u16x8 qf[8];
#pragma unroll
  for (int dc = 0; dc < 8; ++dc) qf[dc] = *(const u16x8*)(qbase + dc * 16 + hi * 8);

  f32x16 o[4] = {};
  float m_run = -3e38f, l_run = 0.f;
  const int ntiles = CAUSAL ? qt * 4 + 4 : SEQ / 64;
  const float scale = 0.088388347648318447f;  // 1/sqrt(128)
  const float defer_thr = 90.50966799187809f; // 8 / scale

  auto stage = [&](int kt, int buf) {
#pragma unroll
    for (int i = 0; i < 2; ++i) {
      int c = i * 512 + tid;
      int krow = c >> 4, ks = c & 15;
      gll16(kbase + (size_t)(kt * 64 + krow) * kstr + ((ks ^ (krow & 15)) * 8),
            Kl + (size_t)buf * 8192 + (size_t)c * 8);
      int vd = c >> 3, vs = c & 7;
      gll16(vbase + (size_t)vd * SEQ + kt * 64 + ((vs ^ (vd & 7)) * 8),
            Vl + (size_t)buf * 8192 + (size_t)c * 8);
    }
  };

  stage(0, 0);
  stage(1, 1);

  for (int kt = 0; kt < ntiles; ++kt) {
    if (kt + 1 < ntiles) {
      asm volatile("s_waitcnt vmcnt(4)" ::: "memory");
    } else {
      asm volatile("s_waitcnt vmcnt(0)" ::: "memory");
    }
    __builtin_amdgcn_sched_barrier(0);
    __syncthreads();
    const u16* Kb = Kl + (size_t)(kt & 1) * 8192;
    const u16* Vb = Vl + (size_t)(kt & 1) * 8192;

    if (!(CAUSAL && kt * 64 > qw0 + 31)) {
      f32x16 s01[2] = {};
#pragma unroll
      for (int k2 = 0; k2 < 2; ++k2) {
        int key = k2 * 32 + lo;
#pragma unroll
        for (int mf = 0; mf < 8; ++mf) {
          int dc = mf * 2 + hi;
          u16x8 kf = *(const u16x8*)(Kb + key * 128 + ((dc ^ (key & 15)) * 8));
          s01[k2] = mfma32(kf, qf[mf], s01[k2]);
        }
      }

      float sv[32];
      float pm = -3e38f;
#pragma unroll
      for (int k2 = 0; k2 < 2; ++k2)
#pragma unroll
        for (int r = 0; r < 16; ++r) {
          float v = s01[k2][r];
          if (CAUSAL) {
            int key = kt * 64 + k2 * 32 + (r & 3) + 8 * (r >> 2) + 4 * hi;
            if (key > qg) v = -3e38f;
          }
          sv[k2 * 16 + r] = v;
          pm = fmaxf(pm, v);
        }
      pm = fmaxf(pm, __shfl_xor(pm, 32, 64));

      const bool defer = __all(pm - m_run <= defer_thr);
      float mn = defer ? m_run : fmaxf(m_run, pm);
      float corr = defer ? 1.0f : __expf((m_run - mn) * scale);
      m_run = mn;

      float ps = 0.f;
      u16x8 pf[4];
#pragma unroll
      for (int k2 = 0; k2 < 2; ++k2)
#pragma unroll
        for (int hf = 0; hf < 2; ++hf) {
          float p8[8];
#pragma unroll
          for (int j = 0; j < 8; ++j) {
            p8[j] = __expf((sv[k2 * 16 + hf * 8 + j] - mn) * scale);
            ps += p8[j];
          }
          unsigned w0, w1, w2, w3;
          asm("v_cvt_pk_bf16_f32 %0, %1, %2" : "=v"(w0) : "v"(p8[0]), "v"(p8[1]));
          asm("v_cvt_pk_bf16_f32 %0, %1, %2" : "=v"(w1) : "v"(p8[2]), "v"(p8[3]));
          asm("v_cvt_pk_bf16_f32 %0, %1, %2" : "=v"(w2) : "v"(p8[4]), "v"(p8[5]));
          asm("v_cvt_pk_bf16_f32 %0, %1, %2" : "=v"(w3) : "v"(p8[6]), "v"(p8[7]));
          asm("v_permlane32_swap_b32 %0, %1" : "+v"(w0), "+v"(w2));
          asm("v_permlane32_swap_b32 %0, %1" : "+v"(w1), "+v"(w3));
          u32x4 fr; fr[0] = w0; fr[1] = w1; fr[2] = w2; fr[3] = w3;
          pf[k2 * 2 + hf] = __builtin_bit_cast(u16x8, fr);
        }
      ps += __shfl_xor(ps, 32, 64);

      if (defer) {
        l_run += ps;
      } else {
        l_run = l_run * corr + ps;
#pragma unroll
        for (int mb = 0; mb < 4; ++mb)
#pragma unroll
          for (int r = 0; r < 16; ++r) o[mb][r] *= corr;
      }

#pragma unroll
      for (int kc = 0; kc < 4; ++kc) {
        int vcs = kc * 2 + hi;
#pragma unroll
        for (int mb = 0; mb < 4; ++mb) {
          int d = mb * 32 + lo;
          u16x8 vf = *(const u16x8*)(Vb + d * 64 + ((vcs ^ (d & 7)) * 8));
          o[mb] = mfma32(vf, pf[kc], o[mb]);
        }
      }
    }

    __syncthreads();
    if (kt + 2 < ntiles) stage(kt + 2, kt & 1);
  }

  float inv = 1.0f / l_run;
  u16* ob = outp + ((size_t)b * SEQ + qg) * D_MODEL + h * HD + 4 * hi;
#pragma unroll
  for (int mb = 0; mb < 4; ++mb)
#pragma unroll
    for (int rq = 0; rq < 4; ++rq) {
      u16x4 w;
#pragma unroll
      for (int j = 0; j < 4; ++j) w[j] = f2bf(o[mb][rq * 4 + j] * inv);
      *(u16x4*)(ob + mb * 32 + rq * 8) = w;
    }
}

extern "C" void kernel_launch(void* const* d_in, const int* in_sizes, int n_in,
                              void* d_out, int out_size, void* d_ws, size_t ws_size,
                              hipStream_t stream) {
  const float* x          = (const float*)d_in[0];
  const float* k_ctx      = (const float*)d_in[1];
  const float* v_ctx      = (const float*)d_in[2];
  const float* wq         = (const float*)d_in[3];
  const float* wo_cross   = (const float*)d_in[4];
  const float* norm_q_w   = (const float*)d_in[5];
  const float* wqkv       = (const float*)d_in[6];
  const float* wo_self    = (const float*)d_in[7];
  const float* norm_qkv_w = (const float*)d_in[8];
  const float* ffn_w1     = (const float*)d_in[9];
  const float* ffn_w2     = (const float*)d_in[10];
  const float* ffn_norm_w = (const float*)d_in[11];
  float* out = (float*)d_out;

  char* ws = (char*)d_ws;
  size_t off = 0;
  auto alloc_u16 = [&](size_t n) { u16* p = (u16*)(ws + off); off += n * 2; return p; };
  auto alloc_f32 = [&](size_t n) { float* p = (float*)(ws + off); off += n * 4; return p; };
  u16* wq_bf   = alloc_u16((size_t)2048 * 2048);   // [N][K]
  u16* woc_bf  = alloc_u16((size_t)2048 * 2048);
  u16* wqkv_bf = alloc_u16((size_t)2048 * 6144);
  u16* wos_bf  = alloc_u16((size_t)2048 * 2048);
  u16* w1_bf   = alloc_u16((size_t)2048 * 8192);
  u16* w2_bf   = alloc_u16((size_t)8192 * 2048);
  u16* xn_bf   = alloc_u16((size_t)ROWS * 2048);
  u16* qkv_bf  = alloc_u16((size_t)ROWS * 6144);
  u16* attn_bf = alloc_u16((size_t)ROWS * 2048);
  float* x1    = alloc_f32((size_t)ROWS * 2048);
  float* x2    = alloc_f32((size_t)ROWS * 2048);
  u16* q_bf    = qkv_bf;
  u16* h1_bf   = qkv_bf;                // qkv + attn regions hold FFN hidden
  u16* kc_bf   = (u16*)x2;              // x2 dead until wos output
  u16* vt_ctx  = kc_bf + (size_t)BATCH * SEQ * 4 * HD;   // [b][g][128][SEQ]
  u16* vt_self = (u16*)x2;              // x2 region; consumed before wos writes
  const int n4 = ROWS * 2048 / 4;

  // ---- fused weight prep (one launch) ----
  {
    WTArgs wt;
    const float* s6[6] = {wq, wo_cross, wqkv, wo_self, ffn_w1, ffn_w2};
    u16* d6[6] = {wq_bf, woc_bf, wqkv_bf, wos_bf, w1_bf, w2_bf};
    int K6[6] = {2048, 2048, 2048, 2048, 2048, 8192};
    int N6[6] = {2048, 2048, 6144, 2048, 8192, 2048};
    int s = 0;
    wt.start[0] = 0;
    for (int i = 0; i < 6; ++i) {
      wt.src[i] = s6[i]; wt.dst[i] = d6[i]; wt.K[i] = K6[i]; wt.N[i] = N6[i];
      s += (N6[i] >> 6) * (K6[i] >> 6);
      wt.start[i + 1] = s;
    }
    cast_transpose_all<<<dim3(s), 256, 0, stream>>>(wt);  // s = 14336
  }
  {
    int n8 = (int)((size_t)BATCH * SEQ * 4 * HD / 8);
    cast_kernel<<<dim3((n8 + 255) / 256), dim3(256), 0, stream>>>(k_ctx, kc_bf, n8);
  }
  build_vt_kernel<float><<<dim3(SEQ / 64, HD / 64, BATCH * 4), 256, 0, stream>>>(
      v_ctx, vt_ctx, 4, (size_t)SEQ * 512, (size_t)HD, 512);

  // ---- cross attention (GQA) ----
  rmsnorm_kernel<<<ROWS, 256, 0, stream>>>(x, norm_q_w, xn_bf);
  gemm_n128_kernel<0, 1><<<dim3((ROWS / 256) * (2048 / 128)), 512, 0, stream>>>(
      xn_bf, wq_bf, q_bf, nullptr, nullptr, 2048, 2048);
  attn2_kernel<false, false><<<dim3(SEQ / 256, BATCH * NH), 512, 0, stream>>>(
      q_bf, kc_bf, vt_ctx, attn_bf);
  gemm_n128_kernel<1, 1><<<dim3((ROWS / 256) * (2048 / 128)), 512, 0, stream>>>(
      attn_bf, woc_bf, x1, x, nullptr, 2048, 2048);

  // ---- causal self attention ----
  rmsnorm_kernel<<<ROWS, 256, 0, stream>>>(x1, norm_qkv_w, xn_bf);
  gemm_n128_kernel<4, 1><<<dim3((ROWS / 256) * (6144 / 128)), 512, 0, stream>>>(
      xn_bf, wqkv_bf, qkv_bf, nullptr, vt_self, 6144, 2048);
  attn2_kernel<true, true><<<dim3(SEQ / 256, BATCH * NH), 512, 0, stream>>>(
      qkv_bf, qkv_bf, vt_self, attn_bf);
  gemm_n128_kernel<1, 1><<<dim3((ROWS / 256) * (2048 / 128)), 512, 0, stream>>>(
      attn_bf, wos_bf, x2, x1, nullptr, 2048, 2048);

  // ---- FFN (SiLU) ----
  rmsnorm_kernel<<<ROWS, 256, 0, stream>>>(x2, ffn_norm_w, xn_bf);
  gemm256_kernel<2, 1><<<dim3((ROWS / 256) * (8192 / 256)), 512, 0, stream>>>(
      xn_bf, w1_bf, h1_bf, nullptr, nullptr, 8192, 2048);
  // ffn_w2 split-K=2 on n128: 512 blocks = one full co-resident pass @2/CU.
  // P0 = out region (aliases final out, element-wise safe), P1 = x1 (dead).
  gemm_n128_kernel<3, 2><<<dim3(512), 512, 0, stream>>>(
      h1_bf, w2_bf, out, nullptr, (u16*)x1, 2048, 8192);
  combine_kernel<1><<<dim3((n4 + 255) / 256), 256, 0, stream>>>(
      out, x1, x2, out, n4);
}

// Round 17
// 809.110 us; speedup vs baseline: 1.0189x; 1.0189x over previous
//
#include <hip/hip_runtime.h>
#include <math.h>

typedef unsigned short u16;
typedef __attribute__((ext_vector_type(4))) u16 u16x4;
typedef __attribute__((ext_vector_type(8))) u16 u16x8;
typedef __attribute__((ext_vector_type(8))) __bf16 bf16x8;
typedef __attribute__((ext_vector_type(4))) float f32x4;
typedef __attribute__((ext_vector_type(16))) float f32x16;
typedef __attribute__((ext_vector_type(4))) unsigned u32x4;

#define D_MODEL 2048
#define SEQ 2048
#define BATCH 2
#define NH 16
#define HD 128
#define DFF 8192
#define ROWS (BATCH * SEQ)  // 4096

__device__ __forceinline__ u16 f2bf(float f) {
  union { float f; unsigned u; } v; v.f = f;
  unsigned r = v.u + 0x7FFFu + ((v.u >> 16) & 1u);
  return (u16)(r >> 16);
}
__device__ __forceinline__ u16 to_bf16(float f) { return f2bf(f); }
__device__ __forceinline__ u16 to_bf16(u16 v) { return v; }

__device__ __forceinline__ f32x4 mfma16(u16x8 a, u16x8 b, f32x4 c) {
  return __builtin_amdgcn_mfma_f32_16x16x32_bf16(
      __builtin_bit_cast(bf16x8, a), __builtin_bit_cast(bf16x8, b), c, 0, 0, 0);
}
__device__ __forceinline__ f32x16 mfma32(u16x8 a, u16x8 b, f32x16 c) {
  return __builtin_amdgcn_mfma_f32_32x32x16_bf16(
      __builtin_bit_cast(bf16x8, a), __builtin_bit_cast(bf16x8, b), c, 0, 0, 0);
}

__device__ __forceinline__ void gll16(const void* g, void* l) {
  __builtin_amdgcn_global_load_lds(
      (const __attribute__((address_space(1))) void*)g,
      (__attribute__((address_space(3))) void*)l, 16, 0, 0);
}

// ---------------- fp32 -> bf16 bulk cast ----------------
__global__ __launch_bounds__(256) void cast_kernel(const float* __restrict__ in,
                                                   u16* __restrict__ out, int n8) {
  int i = blockIdx.x * 256 + threadIdx.x;
  if (i >= n8) return;
  const float4* p = (const float4*)in + (size_t)i * 2;
  float4 a = p[0], b = p[1];
  u16x8 o;
  o[0] = f2bf(a.x); o[1] = f2bf(a.y); o[2] = f2bf(a.z); o[3] = f2bf(a.w);
  o[4] = f2bf(b.x); o[5] = f2bf(b.y); o[6] = f2bf(b.z); o[7] = f2bf(b.w);
  *((u16x8*)out + i) = o;
}

// --------- fused fp32 [K][N] -> bf16 [N][K] transpose-cast, all 6 weights ---
struct WTArgs {
  const float* src[6];
  u16* dst[6];
  int K[6], N[6];
  int start[7];
};

__global__ __launch_bounds__(256) void cast_transpose_all(WTArgs a) {
  __shared__ float tile[64][69];
  int b = blockIdx.x;
  int wi = 0;
#pragma unroll
  for (int i = 0; i < 6; ++i)
    if (b >= a.start[i + 1]) wi = i + 1;
  const float* src = a.src[wi];
  u16* dst = a.dst[wi];
  int K = a.K[wi], N = a.N[wi];
  int t = b - a.start[wi];
  int cols = N >> 6;
  int n0 = (t % cols) * 64, k0 = (t / cols) * 64;
  int rr = threadIdx.x >> 4, cc = (threadIdx.x & 15) * 4;
#pragma unroll
  for (int pp = 0; pp < 4; ++pp) {
    int kk = pp * 16 + rr;
    *(float4*)&tile[kk][cc] = *(const float4*)(src + (size_t)(k0 + kk) * N + n0 + cc);
  }
  __syncthreads();
#pragma unroll
  for (int pp = 0; pp < 4; ++pp) {
    int d = pp * 16 + rr;
    u16x4 w;
#pragma unroll
    for (int j = 0; j < 4; ++j) w[j] = f2bf(tile[cc + j][d]);
    *(u16x4*)(dst + (size_t)(n0 + d) * K + k0 + cc) = w;
  }
}

// ---------------- build V^T (cross only): [SEQ][128] -> [128][SEQ] bf16 -----
template <typename ST>
__global__ __launch_bounds__(256) void build_vt_kernel(
    const ST* __restrict__ src, u16* __restrict__ dst, int HZ,
    size_t src_b_stride, size_t src_h_stride, int src_tok_stride) {
  __shared__ u16 tl[64][72];
  int z = blockIdx.z, zb = z / HZ, zh = z % HZ;
  const ST* s = src + (size_t)zb * src_b_stride + (size_t)zh * src_h_stride;
  int t0 = blockIdx.x * 64, d0 = blockIdx.y * 64;
  int rr = threadIdx.x >> 4, cc = (threadIdx.x & 15) * 4;
#pragma unroll
  for (int pp = 0; pp < 4; ++pp) {
    int t = pp * 16 + rr;
    const ST* sp = s + (size_t)(t0 + t) * src_tok_stride + d0 + cc;
#pragma unroll
    for (int j = 0; j < 4; ++j) tl[t][cc + j] = to_bf16(sp[j]);
  }
  __syncthreads();
  u16* dp = dst + (size_t)z * HD * SEQ;
#pragma unroll
  for (int pp = 0; pp < 4; ++pp) {
    int d = pp * 16 + rr;
    u16x4 w;
#pragma unroll
    for (int j = 0; j < 4; ++j) w[j] = tl[cc + j][d];
    *(u16x4*)(dp + (size_t)(d0 + d) * SEQ + t0 + cc) = w;
  }
}

// ---------------- RMSNorm (fp32 in, bf16 out) ----------------
__global__ __launch_bounds__(256) void rmsnorm_kernel(const float* __restrict__ x,
                                                      const float* __restrict__ w,
                                                      u16* __restrict__ out) {
  __shared__ float red[4];
  int row = blockIdx.x, t = threadIdx.x;
  const float4* xr = (const float4*)(x + (size_t)row * D_MODEL);
  float4 a = xr[t * 2], b = xr[t * 2 + 1];
  float ss = a.x * a.x + a.y * a.y + a.z * a.z + a.w * a.w +
             b.x * b.x + b.y * b.y + b.z * b.z + b.w * b.w;
#pragma unroll
  for (int m = 1; m < 64; m <<= 1) ss += __shfl_xor(ss, m, 64);
  if ((t & 63) == 0) red[t >> 6] = ss;
  __syncthreads();
  float tot = red[0] + red[1] + red[2] + red[3];
  float sc = rsqrtf(tot * (1.0f / D_MODEL) + 1e-6f);
  const float4* wr = (const float4*)w;
  float4 wa = wr[t * 2], wb = wr[t * 2 + 1];
  u16x8 o;
  o[0] = f2bf(a.x * sc * wa.x); o[1] = f2bf(a.y * sc * wa.y);
  o[2] = f2bf(a.z * sc * wa.z); o[3] = f2bf(a.w * sc * wa.w);
  o[4] = f2bf(b.x * sc * wb.x); o[5] = f2bf(b.y * sc * wb.y);
  o[6] = f2bf(b.z * sc * wb.z); o[7] = f2bf(b.w * sc * wb.w);
  *((u16x8*)(out + (size_t)row * D_MODEL) + t) = o;
}

// ---------------- split-K combine (only ffn_w2) ----------------
template <int MODE>
__global__ __launch_bounds__(256) void combine_kernel(
    const float* __restrict__ p0, const float* __restrict__ p1,
    const float* __restrict__ res, void* __restrict__ outv, int n4) {
  int i = blockIdx.x * 256 + threadIdx.x;
  if (i >= n4) return;
  float4 a = ((const float4*)p0)[i];
  float4 b = ((const float4*)p1)[i];
  if (MODE == 1) {
    float4 r = ((const float4*)res)[i];
    float4 o;
    o.x = r.x + a.x + b.x; o.y = r.y + a.y + b.y;
    o.z = r.z + a.z + b.z; o.w = r.w + a.w + b.w;
    ((float4*)outv)[i] = o;
  } else {
    u16x4 o;
    o[0] = f2bf(a.x + b.x); o[1] = f2bf(a.y + b.y);
    o[2] = f2bf(a.z + b.z); o[3] = f2bf(a.w + b.w);
    ((u16x4*)outv)[i] = o;
  }
}

// ============ 256x256 8-wave pipelined GEMM (round-14 verified BEST) ========
// 4 phases/K-tile, ds_read prefetch in odd phases, waits only at odd phases.
#define LOADFRAGS(BASE)                                                        \
  {                                                                            \
    const u16* SA = S + (BASE);                                                \
    const u16* SB = SA + 8192;                                                 \
    _Pragma("unroll") for (int m = 0; m < 8; ++m) {                            \
      int row = wm * 128 + m * 16 + r16;                                       \
      aF[m] = *(const u16x8*)(SA + row * 32 + ((kg ^ ((row >> 1) & 3)) << 3)); \
    }                                                                          \
    _Pragma("unroll") for (int n = 0; n < 4; ++n) {                            \
      int row = wn * 64 + n * 16 + r16;                                        \
      bF[n] = *(const u16x8*)(SB + row * 32 + ((kg ^ ((row >> 1) & 3)) << 3)); \
    }                                                                          \
  }

#define MFMA_HALF(HH)                                                          \
  __builtin_amdgcn_s_setprio(1);                                               \
  _Pragma("unroll") for (int m = 0; m < 8; ++m) {                              \
    acc[m][2 * (HH)] = mfma16(aF[m], bF[2 * (HH)], acc[m][2 * (HH)]);          \
    acc[m][2 * (HH) + 1] =                                                     \
        mfma16(aF[m], bF[2 * (HH) + 1], acc[m][2 * (HH) + 1]);                 \
  }                                                                            \
  __builtin_amdgcn_s_setprio(0);

#define GPH_E(T, P, VM, DOW, ISSUE, FIRST)                                     \
  {                                                                            \
    if (ISSUE) issue_half(4 * (T) + (P) + 4);                                  \
    if (DOW) {                                                                 \
      asm volatile("s_waitcnt vmcnt(" #VM ")" ::: "memory");                   \
      __builtin_amdgcn_sched_barrier(0);                                       \
    }                                                                          \
    __builtin_amdgcn_s_barrier();                                              \
    if (FIRST) LOADFRAGS((((((T) & 1) << 2) | (P)) << 13));                    \
    MFMA_HALF(0)                                                               \
    __builtin_amdgcn_s_barrier();                                              \
  }

#define GPH_O(T, P, VM, DOW, ISSUE, PF)                                        \
  {                                                                            \
    if (ISSUE) issue_half(4 * (T) + (P) + 4);                                  \
    if (DOW) {                                                                 \
      asm volatile("s_waitcnt vmcnt(" #VM ")" ::: "memory");                   \
      __builtin_amdgcn_sched_barrier(0);                                       \
    }                                                                          \
    __builtin_amdgcn_s_barrier();                                              \
    MFMA_HALF(1)                                                               \
    if (PF) {                                                                  \
      if ((P) == 1) {                                                          \
        LOADFRAGS((((((T) & 1) << 2) | 2) << 13));                             \
      } else {                                                                 \
        LOADFRAGS(((((T) + 1) & 1) << 2) << 13);                               \
      }                                                                        \
    }                                                                          \
    __builtin_amdgcn_s_barrier();                                              \
  }

template <int EPI, int SPLIT>
__global__ __launch_bounds__(512, 1) void gemm256_kernel(
    const u16* __restrict__ A, const u16* __restrict__ Bt, void* __restrict__ Cv,
    float* __restrict__ Cv2, const float* __restrict__ res, int N, int K) {
  __shared__ __align__(16) u16 S[8 * 8192];
  const int tid = threadIdx.x, lane = tid & 63, wave = tid >> 6;
  const int wm = wave >> 2, wn = wave & 3;
  const int r16 = lane & 15, kg = lane >> 4;
  const int cols = N >> 8;
  const int cpx = gridDim.x >> 3;
  const int bid = blockIdx.x;
  const int swz = (bid & 7) * cpx + (bid >> 3);
  const int tiles = gridDim.x / SPLIT;
  const int tile = swz % tiles, kslice = swz / tiles;
  const int bm = (tile / cols) * 256, bn = (tile % cols) * 256;
  const int Ksub = K / SPLIT;
  const int koff = kslice * Ksub;
  const int nt = Ksub >> 6;

  auto issue_half = [&](int h) {
    int p = h & 3, t = h >> 2;
    const u16* src = (p & 1) ? (Bt + (size_t)bn * K) : (A + (size_t)bm * K);
    int kbase = koff + t * 64 + (p >> 1) * 32;
    u16* ldst = S + ((((t & 1) << 2) | p) << 13);
#pragma unroll
    for (int i = 0; i < 2; ++i) {
      int c = i * 512 + tid;
      int row = c >> 2, ch = c & 3;
      int kc = ch ^ ((row >> 1) & 3);
      gll16(src + (size_t)row * K + kbase + kc * 8, ldst + c * 8);
    }
  };

  u16x8 aF[8], bF[4];
  f32x4 acc[8][4] = {};

  issue_half(0); issue_half(1); issue_half(2); issue_half(3);
  GPH_E(0, 0, 6, true, true, true);
  GPH_O(0, 1, 4, true, true, true);
  GPH_E(0, 2, 0, false, true, false);
  GPH_O(0, 3, 4, true, true, true);
  for (int t = 1; t < nt - 1; ++t) {
    GPH_E(t, 0, 0, false, true, false);
    GPH_O(t, 1, 4, true, true, true);
    GPH_E(t, 2, 0, false, true, false);
    GPH_O(t, 3, 4, true, true, true);
  }
  {
    const int t = nt - 1;
    GPH_E(t, 0, 0, false, false, false);
    GPH_O(t, 1, 0, true, false, true);
    GPH_E(t, 2, 0, false, false, false);
    GPH_O(t, 3, 0, false, false, false);
  }

  float* Pp = (EPI == 3) ? (kslice ? Cv2 : (float*)Cv) : nullptr;
#pragma unroll
  for (int m = 0; m < 8; ++m) {
    int r0 = bm + wm * 128 + m * 16 + kg * 4;
#pragma unroll
    for (int n = 0; n < 4; ++n) {
      int cc = bn + wn * 64 + n * 16 + r16;
#pragma unroll
      for (int r = 0; r < 4; ++r) {
        size_t idx = (size_t)(r0 + r) * N + cc;
        float v = acc[m][n][r];
        if (EPI == 3) {
          Pp[idx] = v;
        } else if (EPI == 1) {
          ((float*)Cv)[idx] = res[idx] + v;
        } else if (EPI == 0) {
          ((u16*)Cv)[idx] = f2bf(v);
        } else {
          float s = v / (1.0f + __expf(-v));
          ((u16*)Cv)[idx] = f2bf(s);
        }
      }
    }
  }
}

// ============ 256x128 GEMM, 2-region double-buffer, 2 blocks/CU =============
#define NPH2(T, P, VM, ISSUE)                                                  \
  {                                                                            \
    if (ISSUE) issue_pair(2 * (T) + (P) + 1);                                  \
    asm volatile("s_waitcnt vmcnt(" #VM ")" ::: "memory");                     \
    __builtin_amdgcn_sched_barrier(0);                                         \
    __builtin_amdgcn_s_barrier();                                              \
    const u16* SA = S + (((2 * (T) + (P)) & 1) * 12288);                       \
    const u16* SB = SA + 8192;                                                 \
    u16x8 aF[4], bF[4];                                                        \
    _Pragma("unroll") for (int m = 0; m < 4; ++m) {                            \
      int row = wm * 64 + m * 16 + r16;                                        \
      aF[m] = *(const u16x8*)(SA + row * 32 + ((kg ^ ((row >> 1) & 3)) << 3)); \
    }                                                                          \
    _Pragma("unroll") for (int n = 0; n < 4; ++n) {                            \
      int row = wn * 64 + n * 16 + r16;                                        \
      bF[n] = *(const u16x8*)(SB + row * 32 + ((kg ^ ((row >> 1) & 3)) << 3)); \
    }                                                                          \
    __builtin_amdgcn_s_setprio(1);                                             \
    _Pragma("unroll") for (int m = 0; m < 4; ++m)                              \
      _Pragma("unroll") for (int n = 0; n < 4; ++n)                            \
        acc[m][n] = mfma16(aF[m], bF[n], acc[m][n]);                           \
    __builtin_amdgcn_s_setprio(0);                                             \
    __builtin_amdgcn_s_barrier();                                              \
  }

template <int EPI, int SPLIT>
__global__ __launch_bounds__(512, 4) void gemm_n128_kernel(
    const u16* __restrict__ A, const u16* __restrict__ Bt, void* __restrict__ Cv,
    const float* __restrict__ res, u16* __restrict__ vt, int N, int K) {
  __shared__ __align__(16) u16 S[2 * 12288];  // 48 KB
  const int tid = threadIdx.x, lane = tid & 63, wave = tid >> 6;
  const int wm = wave >> 1, wn = wave & 1;
  const int r16 = lane & 15, kg = lane >> 4;
  const int cols = N >> 7;
  const int cpx = gridDim.x >> 3;
  const int bid = blockIdx.x;
  const int swz = (bid & 7) * cpx + (bid >> 3);
  const int tiles = gridDim.x / SPLIT;
  const int tile = swz % tiles, kslice = swz / tiles;
  const int bm = (tile / cols) * 256, bn = (tile % cols) * 128;
  const int Ksub = K / SPLIT;
  const int koff = kslice * Ksub;
  const int nt = Ksub >> 6;

  auto issue_pair = [&](int g) {
    int p = g & 1, t = g >> 1;
    int kbase = koff + t * 64 + p * 32;
    u16* reg = S + ((g & 1) * 12288);
#pragma unroll
    for (int i = 0; i < 2; ++i) {
      int c = i * 512 + tid;
      int row = c >> 2, ch = c & 3;
      int kc = ch ^ ((row >> 1) & 3);
      gll16(A + (size_t)(bm + row) * K + kbase + kc * 8, reg + c * 8);
    }
    {
      int row = tid >> 2, ch = tid & 3;
      int kc = ch ^ ((row >> 1) & 3);
      gll16(Bt + (size_t)(bn + row) * K + kbase + kc * 8, reg + 8192 + tid * 8);
    }
  };

  f32x4 acc[4][4] = {};

  issue_pair(0);
  for (int t = 0; t < nt - 1; ++t) {
    NPH2(t, 0, 3, true);
    NPH2(t, 1, 3, true);
  }
  NPH2(nt - 1, 0, 3, true);
  NPH2(nt - 1, 1, 0, false);

  const bool vmode = (EPI == 4) && (bn >= 4096);
#pragma unroll
  for (int m = 0; m < 4; ++m) {
    int r0 = bm + wm * 64 + m * 16 + kg * 4;
#pragma unroll
    for (int n = 0; n < 4; ++n) {
      int cc = bn + wn * 64 + n * 16 + r16;
      if (vmode) {
        int c2 = cc - 4096;
        int z = (r0 >> 11) * NH + (c2 >> 7);
        int d = c2 & 127;
        int t0 = r0 & (SEQ - 1);
        u16x4 w;
#pragma unroll
        for (int r = 0; r < 4; ++r) w[r] = f2bf(acc[m][n][r]);
        *(u16x4*)(vt + ((size_t)z * HD + d) * SEQ + t0) = w;
      } else {
#pragma unroll
        for (int r = 0; r < 4; ++r) {
          size_t idx = (size_t)(r0 + r) * N + cc;
          float v = acc[m][n][r];
          if (EPI == 1) {
            ((float*)Cv)[idx] = res[idx] + v;
          } else {
            ((u16*)Cv)[idx] = f2bf(v);
          }
        }
      }
    }
  }
}

// ---------------- flash attention v3: K/V double-buffered (verified r11) ----
template <bool CAUSAL, bool SELF>
__global__ __launch_bounds__(512, 2) void attn2_kernel(
    const u16* __restrict__ qp, const u16* __restrict__ kp,
    const u16* __restrict__ vtp, u16* __restrict__ outp) {
  __shared__ __align__(16) u16 Kl[2 * 64 * 128];   // 32 KB
  __shared__ __align__(16) u16 Vl[2 * 128 * 64];   // 32 KB
  const int tid = threadIdx.x, lane = tid & 63, wave = tid >> 6;
  const int lo = lane & 31, hi = lane >> 5;
  const int qt = blockIdx.x, bh = blockIdx.y, b = bh >> 4, h = bh & 15;
  const int qw0 = qt * 256 + wave * 32;
  const int qg = qw0 + lo;
  const size_t qstr = SELF ? 6144 : 2048;
  const size_t kstr = SELF ? 6144 : 512;
  const u16* qbase = qp + ((size_t)b * SEQ + qg) * qstr + h * HD;
  const u16* kbase = kp + (size_t)b * SEQ * kstr + (SELF ? (2048 + h * HD) : ((h >> 2) * HD));
  const u16* vbase = vtp + (size_t)(SELF ? (b * NH + h) : (b * 4 + (h >> 2))) * HD * SEQ;

  u16x8 qf[8];
#pragma unroll
  for (int dc = 0; dc < 8; ++dc) qf[dc] = *(const u16x8*)(qbase + dc * 16 + hi * 8);

  f32x16 o[4] = {};
  float m_run = -3e38f, l_run = 0.f;
  const int ntiles = CAUSAL ? qt * 4 + 4 : SEQ / 64;
  const float scale = 0.088388347648318447f;  // 1/sqrt(128)
  const float defer_thr = 90.50966799187809f; // 8 / scale

  auto stage = [&](int kt, int buf) {
#pragma unroll
    for (int i = 0; i < 2; ++i) {
      int c = i * 512 + tid;
      int krow = c >> 4, ks = c & 15;
      gll16(kbase + (size_t)(kt * 64 + krow) * kstr + ((ks ^ (krow & 15)) * 8),
            Kl + (size_t)buf * 8192 + (size_t)c * 8);
      int vd = c >> 3, vs = c & 7;
      gll16(vbase + (size_t)vd * SEQ + kt * 64 + ((vs ^ (vd & 7)) * 8),
            Vl + (size_t)buf * 8192 + (size_t)c * 8);
    }
  };

  stage(0, 0);
  stage(1, 1);

  for (int kt = 0; kt < ntiles; ++kt) {
    if (kt + 1 < ntiles) {
      asm volatile("s_waitcnt vmcnt(4)" ::: "memory");
    } else {
      asm volatile("s_waitcnt vmcnt(0)" ::: "memory");
    }
    __builtin_amdgcn_sched_barrier(0);
    __syncthreads();
    const u16* Kb = Kl + (size_t)(kt & 1) * 8192;
    const u16* Vb = Vl + (size_t)(kt & 1) * 8192;

    if (!(CAUSAL && kt * 64 > qw0 + 31)) {
      f32x16 s01[2] = {};
#pragma unroll
      for (int k2 = 0; k2 < 2; ++k2) {
        int key = k2 * 32 + lo;
#pragma unroll
        for (int mf = 0; mf < 8; ++mf) {
          int dc = mf * 2 + hi;
          u16x8 kf = *(const u16x8*)(Kb + key * 128 + ((dc ^ (key & 15)) * 8));
          s01[k2] = mfma32(kf, qf[mf], s01[k2]);
        }
      }

      float sv[32];
      float pm = -3e38f;
#pragma unroll
      for (int k2 = 0; k2 < 2; ++k2)
#pragma unroll
        for (int r = 0; r < 16; ++r) {
          float v = s01[k2][r];
          if (CAUSAL) {
            int key = kt * 64 + k2 * 32 + (r & 3) + 8 * (r >> 2) + 4 * hi;
            if (key > qg) v = -3e38f;
          }
          sv[k2 * 16 + r] = v;
          pm = fmaxf(pm, v);
        }
      pm = fmaxf(pm, __shfl_xor(pm, 32, 64));

      const bool defer = __all(pm - m_run <= defer_thr);
      float mn = defer ? m_run : fmaxf(m_run, pm);
      float corr = defer ? 1.0f : __expf((m_run - mn) * scale);
      m_run = mn;

      float ps = 0.f;
      u16x8 pf[4];
#pragma unroll
      for (int k2 = 0; k2 < 2; ++k2)
#pragma unroll
        for (int hf = 0; hf < 2; ++hf) {
          float p8[8];
#pragma unroll
          for (int j = 0; j < 8; ++j) {
            p8[j] = __expf((sv[k2 * 16 + hf * 8 + j] - mn) * scale);
            ps += p8[j];
          }
          unsigned w0, w1, w2, w3;
          asm("v_cvt_pk_bf16_f32 %0, %1, %2" : "=v"(w0) : "v"(p8[0]), "v"(p8[1]));
          asm("v_cvt_pk_bf16_f32 %0, %1, %2" : "=v"(w1) : "v"(p8[2]), "v"(p8[3]));
          asm("v_cvt_pk_bf16_f32 %0, %1, %2" : "=v"(w2) : "v"(p8[4]), "v"(p8[5]));
          asm("v_cvt_pk_bf16_f32 %0, %1, %2" : "=v"(w3) : "v"(p8[6]), "v"(p8[7]));
          asm("v_permlane32_swap_b32 %0, %1" : "+v"(w0), "+v"(w2));
          asm("v_permlane32_swap_b32 %0, %1" : "+v"(w1), "+v"(w3));
          u32x4 fr; fr[0] = w0; fr[1] = w1; fr[2] = w2; fr[3] = w3;
          pf[k2 * 2 + hf] = __builtin_bit_cast(u16x8, fr);
        }
      ps += __shfl_xor(ps, 32, 64);

      if (defer) {
        l_run += ps;
      } else {
        l_run = l_run * corr + ps;
#pragma unroll
        for (int mb = 0; mb < 4; ++mb)
#pragma unroll
          for (int r = 0; r < 16; ++r) o[mb][r] *= corr;
      }

#pragma unroll
      for (int kc = 0; kc < 4; ++kc) {
        int vcs = kc * 2 + hi;
#pragma unroll
        for (int mb = 0; mb < 4; ++mb) {
          int d = mb * 32 + lo;
          u16x8 vf = *(const u16x8*)(Vb + d * 64 + ((vcs ^ (d & 7)) * 8));
          o[mb] = mfma32(vf, pf[kc], o[mb]);
        }
      }
    }

    __syncthreads();
    if (kt + 2 < ntiles) stage(kt + 2, kt & 1);
  }

  float inv = 1.0f / l_run;
  u16* ob = outp + ((size_t)b * SEQ + qg) * D_MODEL + h * HD + 4 * hi;
#pragma unroll
  for (int mb = 0; mb < 4; ++mb)
#pragma unroll
    for (int rq = 0; rq < 4; ++rq) {
      u16x4 w;
#pragma unroll
      for (int j = 0; j < 4; ++j) w[j] = f2bf(o[mb][rq * 4 + j] * inv);
      *(u16x4*)(ob + mb * 32 + rq * 8) = w;
    }
}

extern "C" void kernel_launch(void* const* d_in, const int* in_sizes, int n_in,
                              void* d_out, int out_size, void* d_ws, size_t ws_size,
                              hipStream_t stream) {
  const float* x          = (const float*)d_in[0];
  const float* k_ctx      = (const float*)d_in[1];
  const float* v_ctx      = (const float*)d_in[2];
  const float* wq         = (const float*)d_in[3];
  const float* wo_cross   = (const float*)d_in[4];
  const float* norm_q_w   = (const float*)d_in[5];
  const float* wqkv       = (const float*)d_in[6];
  const float* wo_self    = (const float*)d_in[7];
  const float* norm_qkv_w = (const float*)d_in[8];
  const float* ffn_w1     = (const float*)d_in[9];
  const float* ffn_w2     = (const float*)d_in[10];
  const float* ffn_norm_w = (const float*)d_in[11];
  float* out = (float*)d_out;

  char* ws = (char*)d_ws;
  size_t off = 0;
  auto alloc_u16 = [&](size_t n) { u16* p = (u16*)(ws + off); off += n * 2; return p; };
  auto alloc_f32 = [&](size_t n) { float* p = (float*)(ws + off); off += n * 4; return p; };
  u16* wq_bf   = alloc_u16((size_t)2048 * 2048);   // [N][K]
  u16* woc_bf  = alloc_u16((size_t)2048 * 2048);
  u16* wqkv_bf = alloc_u16((size_t)2048 * 6144);
  u16* wos_bf  = alloc_u16((size_t)2048 * 2048);
  u16* w1_bf   = alloc_u16((size_t)2048 * 8192);
  u16* w2_bf   = alloc_u16((size_t)8192 * 2048);
  u16* xn_bf   = alloc_u16((size_t)ROWS * 2048);
  u16* qkv_bf  = alloc_u16((size_t)ROWS * 6144);
  u16* attn_bf = alloc_u16((size_t)ROWS * 2048);
  float* x1    = alloc_f32((size_t)ROWS * 2048);
  float* x2    = alloc_f32((size_t)ROWS * 2048);
  u16* q_bf    = qkv_bf;
  u16* h1_bf   = qkv_bf;                // qkv + attn regions hold FFN hidden
  u16* kc_bf   = (u16*)x2;              // x2 dead until wos output
  u16* vt_ctx  = kc_bf + (size_t)BATCH * SEQ * 4 * HD;   // [b][g][128][SEQ]
  u16* vt_self = (u16*)x2;              // x2 region; consumed before wos writes
  const int n4 = ROWS * 2048 / 4;

  // ---- fused weight prep (one launch) ----
  {
    WTArgs wt;
    const float* s6[6] = {wq, wo_cross, wqkv, wo_self, ffn_w1, ffn_w2};
    u16* d6[6] = {wq_bf, woc_bf, wqkv_bf, wos_bf, w1_bf, w2_bf};
    int K6[6] = {2048, 2048, 2048, 2048, 2048, 8192};
    int N6[6] = {2048, 2048, 6144, 2048, 8192, 2048};
    int s = 0;
    wt.start[0] = 0;
    for (int i = 0; i < 6; ++i) {
      wt.src[i] = s6[i]; wt.dst[i] = d6[i]; wt.K[i] = K6[i]; wt.N[i] = N6[i];
      s += (N6[i] >> 6) * (K6[i] >> 6);
      wt.start[i + 1] = s;
    }
    cast_transpose_all<<<dim3(s), 256, 0, stream>>>(wt);  // s = 14336
  }
  {
    int n8 = (int)((size_t)BATCH * SEQ * 4 * HD / 8);
    cast_kernel<<<dim3((n8 + 255) / 256), dim3(256), 0, stream>>>(k_ctx, kc_bf, n8);
  }
  build_vt_kernel<float><<<dim3(SEQ / 64, HD / 64, BATCH * 4), 256, 0, stream>>>(
      v_ctx, vt_ctx, 4, (size_t)SEQ * 512, (size_t)HD, 512);

  // ---- cross attention (GQA) ----
  rmsnorm_kernel<<<ROWS, 256, 0, stream>>>(x, norm_q_w, xn_bf);
  gemm_n128_kernel<0, 1><<<dim3((ROWS / 256) * (2048 / 128)), 512, 0, stream>>>(
      xn_bf, wq_bf, q_bf, nullptr, nullptr, 2048, 2048);
  attn2_kernel<false, false><<<dim3(SEQ / 256, BATCH * NH), 512, 0, stream>>>(
      q_bf, kc_bf, vt_ctx, attn_bf);
  gemm_n128_kernel<1, 1><<<dim3((ROWS / 256) * (2048 / 128)), 512, 0, stream>>>(
      attn_bf, woc_bf, x1, x, nullptr, 2048, 2048);

  // ---- causal self attention ----
  rmsnorm_kernel<<<ROWS, 256, 0, stream>>>(x1, norm_qkv_w, xn_bf);
  gemm_n128_kernel<4, 1><<<dim3((ROWS / 256) * (6144 / 128)), 512, 0, stream>>>(
      xn_bf, wqkv_bf, qkv_bf, nullptr, vt_self, 6144, 2048);
  attn2_kernel<true, true><<<dim3(SEQ / 256, BATCH * NH), 512, 0, stream>>>(
      qkv_bf, qkv_bf, vt_self, attn_bf);
  gemm_n128_kernel<1, 1><<<dim3((ROWS / 256) * (2048 / 128)), 512, 0, stream>>>(
      attn_bf, wos_bf, x2, x1, nullptr, 2048, 2048);

  // ---- FFN (SiLU) ----
  rmsnorm_kernel<<<ROWS, 256, 0, stream>>>(x2, ffn_norm_w, xn_bf);
  gemm256_kernel<2, 1><<<dim3((ROWS / 256) * (8192 / 256)), 512, 0, stream>>>(
      xn_bf, w1_bf, h1_bf, nullptr, nullptr, 8192, 2048);
  // ffn_w2 split-K=2 on gemm256 (round-7-verified): P0 = out, P1 = x1 (dead)
  gemm256_kernel<3, 2><<<dim3(256), 512, 0, stream>>>(
      h1_bf, w2_bf, out, x1, nullptr, 2048, 8192);
  combine_kernel<1><<<dim3((n4 + 255) / 256), 256, 0, stream>>>(
      out, x1, x2, out, n4);
}